// Round 21
// baseline (60.637 us; speedup 1.0000x reference)
//
#include <hip/hip_runtime.h>

#define BB 8
#define CC 64
#define HH 96
#define WW 96
#define OO 64
#define KK 3
#define K2 9
#define HW (HH*WW)      // 9216
#define NOFF 18
#define NPIX (BB*HW)    // 73728
#define MT 128          // pixels per fused block: 4 rows x 32 cols
#define NTILE (HW/MT)   // 72 tiles per image (24 tile-rows x 3 tile-cols)
#define NXCD 8
#define WR 8
#define WC 36
#define NWIN (WR*WC)    // 288 window pixel-rows, 128 B each (seg-swizzled)
#define OSTR 21         // offs row stride (floats)

typedef _Float16 f16;
typedef __attribute__((ext_vector_type(2))) _Float16 f16x2;
typedef __attribute__((ext_vector_type(4))) _Float16 f16x4;
typedef __attribute__((ext_vector_type(4))) float f32x4;
typedef __attribute__((ext_vector_type(2))) unsigned int uint2v;
typedef __attribute__((ext_vector_type(4))) unsigned int uint4v;

#define MFMA16(a,b,c) __builtin_amdgcn_mfma_f32_16x16x16f16(a,b,c,0,0,0)

__device__ __forceinline__ f16x2 bch(unsigned u) { return __builtin_bit_cast(f16x2, u); }
__device__ __forceinline__ unsigned bcu(f16x2 h) { return __builtin_bit_cast(unsigned, h); }
__device__ __forceinline__ f16x4 fq(unsigned a, unsigned b) {
  uint2v u = {a, b};
  return __builtin_bit_cast(f16x4, u);
}
__device__ __forceinline__ f16x4 fq2(uint2v u) { return __builtin_bit_cast(f16x4, u); }
__device__ __forceinline__ int xcd_remap(int bid, int per) {
  return (bid & 7) * per + (bid >> 3);
}

// ---------------- Kernel T: NCHW fp32 -> NHWC f16 (verified R5) -------------
__global__ __launch_bounds__(256) void transpose_kernel(
    const float* __restrict__ x, unsigned short* __restrict__ xt) {
  int t = threadIdx.x;
  int px = xcd_remap(blockIdx.x, NPIX / 64 / NXCD) * 64 + (t & 63);
  int cg = t >> 6;
  int b = px / HW, hw = px % HW;
  const float* xp = x + (size_t)b * CC * HW + (size_t)(cg * 16) * HW + hw;
  f16 r[16];
  #pragma unroll
  for (int i = 0; i < 16; ++i) r[i] = (f16)xp[i * HW];
  uint4v v0, v1;
  #pragma unroll
  for (int q = 0; q < 4; ++q) {
    f16x2 a = {r[q*2], r[q*2+1]};       v0[q] = bcu(a);
    f16x2 bq = {r[8+q*2], r[8+q*2+1]};  v1[q] = bcu(bq);
  }
  uint4v* dst = (uint4v*)(xt + (size_t)px * CC + cg * 16);
  dst[0] = v0; dst[1] = v1;
}

// ------- Kernel P: merged weight prep (wtx lane-exact + wofx lane-exact) ----
// wtx[k][nb][l][16ch]: c = 16*(l>>4)+e, o = nb*16+(l&15)    (verified R19)
// wofx[kt][n][q][l][4ch]: c = 16q+4*(l>>4)+e, j = n*16+(l&15) (verified R20)
__global__ void prep_kernel(const float* __restrict__ w_dcn,
                            const float* __restrict__ w_off,
                            unsigned short* __restrict__ wtx,
                            unsigned short* __restrict__ wofx) {
  int idx = blockIdx.x * 256 + threadIdx.x;   // 36864 + 18432 = 55296
  if (idx < 36864) {
    int e = idx & 15;
    int l = (idx >> 4) & 63;
    int nb = (idx >> 10) & 3;
    int k = idx >> 12;
    int c = 16 * (l >> 4) + e;
    int o = nb * 16 + (l & 15);
    f16 h = (f16)w_dcn[(o * CC + c) * K2 + k];
    wtx[idx] = __builtin_bit_cast(unsigned short, h);
  } else {
    int i2 = idx - 36864;
    int e = i2 & 3;
    int l = (i2 >> 2) & 63;
    int q = (i2 >> 8) & 3;
    int n = (i2 >> 10) & 1;
    int kt = i2 >> 11;
    int c = q * 16 + 4 * (l >> 4) + e;
    int j = n * 16 + (l & 15);
    f16 h = (f16)((j < NOFF) ? w_off[(j * CC + c) * K2 + kt] : 0.f);
    wofx[i2] = __builtin_bit_cast(unsigned short, h);
  }
}

// ---------------- Kernel F: fused offconv(MFMA) + dcn(MFMA), MT=128 ---------
// Window 8x36 zero-filled (R18/R20-verified), seg-swizzled. po packs window
// ROW indices (<=287, 9 bits; <<7 at use) — R14-style encoding, flag bit31.
// P1: R20-verified MFMA offconv, wave does both j-tiles (A reused).
// P2/P3: R15-verified 9-tap register structure + R19/R20 lane-exact B.
// Epilogue: R15-verified direct store (no reduce — each wave owns its pixels).
#define XWIN_OFF 0
#define OFFS_OFF 36864
#define SMEM_SZ  47616

__global__ __launch_bounds__(512, 3) void fused_kernel(
    const unsigned short* __restrict__ xt,    // [B][HW][C] f16
    const unsigned short* __restrict__ wofx,  // [K2][2][4][64][4] f16
    const float* __restrict__ b_off,          // [18] fp32
    const unsigned short* __restrict__ wtx,   // [K2][4][64][16] f16
    float* __restrict__ out) {
  __shared__ __align__(16) char smem[SMEM_SZ];
  char* xwin = smem + XWIN_OFF;              // 288 x 128 B, seg-swizzled
  float* offs = (float*)(smem + OFFS_OFF);   // [128][21]

  int t = threadIdx.x;
  int blk = xcd_remap(blockIdx.x, NPIX / MT / NXCD);
  int b = blk / NTILE;
  int ti = blk % NTILE;
  int tr = ti / 3, tc = ti % 3;
  int h0 = tr * 4, w0 = tc * 32;             // tile rows h0..h0+3
  int hw0 = h0 * WW + w0;

  const char* xb = (const char*)(xt + (size_t)b * HW * CC);

  // ---- P0: stage window, seg-swizzled, ZERO-fill out-of-image ----
  #pragma unroll
  for (int r = 0; r < 5; ++r) {
    int d = r * 512 + t;                     // 16-B chunk id, 2304 total
    if (d < NWIN * 8) {
      int row = d >> 3, sg = d & 7;
      int wr_ = row / WC, wc_ = row - wr_ * WC;
      int gy = h0 - 2 + wr_;
      int gx = w0 - 2 + wc_;
      uint4v v = (uint4v){0u, 0u, 0u, 0u};
      if (((unsigned)gy < HH) && ((unsigned)gx < WW))
        v = *(const uint4v*)(xb + (size_t)((gy * WW + gx) << 7) + (sg << 4));
      *(uint4v*)&xwin[row * 128 + ((sg ^ (row & 7)) << 4)] = v;
    }
  }
  __syncthreads();

  // wave geometry (verified R9/R12)
  int wv = t >> 6;                           // 0..7 = pixel-tile
  int l  = t & 63;
  int lr = l & 15, lh = l >> 4;

  // ---- P1: offset conv via MFMA (R20 math; both j-tiles per wave) ----
  {
    int p = wv * 16 + lr;                    // A row = this lane's pixel
    int prow = ((p >> 5) + 1) * WC + (p & 31) + 1;  // window row at ky=kx=0
    f32x4 accO0 = (f32x4){0.f, 0.f, 0.f, 0.f};
    f32x4 accO1 = (f32x4){0.f, 0.f, 0.f, 0.f};
    #pragma unroll
    for (int kt = 0; kt < K2; ++kt) {
      int wrow = prow + (kt / 3) * WC + (kt % 3);
      int rs = wrow & 7;
      const char* bp0 = (const char*)wofx + (((size_t)(kt * 2 + 0) * 4) * 64 + l) * 8;
      const char* bp1 = (const char*)wofx + (((size_t)(kt * 2 + 1) * 4) * 64 + l) * 8;
      #pragma unroll
      for (int q = 0; q < 4; ++q) {
        uint2v a2 = *(const uint2v*)&xwin[wrow * 128
                      + ((((q << 1) + (lh >> 1)) ^ rs) << 4) + ((lh & 1) << 3)];
        uint2v b0 = *(const uint2v*)(bp0 + (size_t)q * (64 * 8));
        uint2v b1 = *(const uint2v*)(bp1 + (size_t)q * (64 * 8));
        accO0 = MFMA16(fq2(a2), fq2(b0), accO0);
        accO1 = MFMA16(fq2(a2), fq2(b1), accO1);
      }
    }
    {
      int j = lr;                            // n=0
      float bj = b_off[j];
      #pragma unroll
      for (int r = 0; r < 4; ++r) {
        int px = wv * 16 + lh * 4 + r;       // D row = pixel (R9 map)
        offs[px * OSTR + j] = accO0[r] + bj;
      }
    }
    if (lr < 2) {                            // n=1: j = 16+lr < 18
      int j = 16 + lr;
      float bj = b_off[j];
      #pragma unroll
      for (int r = 0; r < 4; ++r) {
        int px = wv * 16 + lh * 4 + r;
        offs[px * OSTR + j] = accO1[r] + bj;
      }
    }
  }
  __syncthreads();

  // ---- P2: per-lane params for all 9 taps (R15-verified structure) ----
  int Ra = wv * 16 + lr;                     // this lane's pixel (0..127)
  int hpix = h0 + (Ra >> 5), wpix = w0 + (Ra & 31);
  int cB = lh * 32;

  unsigned po01[K2], po23[K2], pw01[K2], pw23[K2];
  unsigned emask = 0;
  #pragma unroll
  for (int k = 0; k < K2; ++k) {
    int ky = k / KK, kx = k % KK;
    float py = offs[Ra * OSTR + 2 * k]     + (float)(hpix - 1 + ky);
    float px = offs[Ra * OSTR + 2 * k + 1] + (float)(wpix - 1 + kx);
    float y0f = floorf(py), x0f = floorf(px);
    float wy = py - y0f, wx = px - x0f;
    int y0 = (int)y0f, x0 = (int)x0f;
    int y1 = y0 + 1, x1 = x0 + 1;
    bool vy0 = (unsigned)y0 < HH, vy1 = (unsigned)y1 < HH;
    bool vx0 = (unsigned)x0 < WW, vx1 = (unsigned)x1 < WW;
    int cy0 = min(max(y0, 0), HH - 1), cy1 = min(max(y1, 0), HH - 1);
    int cx0 = min(max(x0, 0), WW - 1), cx1 = min(max(x1, 0), WW - 1);
    float g00 = (1.f - wy) * (1.f - wx) * ((vy0 && vx0) ? 1.f : 0.f);
    float g01 = (1.f - wy) * wx         * ((vy0 && vx1) ? 1.f : 0.f);
    float g10 = wy * (1.f - wx)         * ((vy1 && vx0) ? 1.f : 0.f);
    float g11 = wy * wx                 * ((vy1 && vx1) ? 1.f : 0.f);
    int ry0 = cy0 - (h0 - 2), ry1 = cy1 - (h0 - 2);
    int rx0 = cx0 - (w0 - 2), rx1 = cx1 - (w0 - 2);
    bool inw = ((unsigned)ry0 < WR) && ((unsigned)ry1 < WR) &&
               ((unsigned)rx0 < WC) && ((unsigned)rx1 < WC);
    if (inw) {   // window ROW indices (<=287, 9 bits) — <<7 at use
      po01[k] = (unsigned)(ry0 * WC + rx0)
              | ((unsigned)(ry0 * WC + rx1) << 16);
      po23[k] = (unsigned)(ry1 * WC + rx0)
              | ((unsigned)(ry1 * WC + rx1) << 16);
    } else {     // image lin indices (<=9215) + flag bit 31 (rare)
      po01[k] = (unsigned)(cy0 * WW + cx0)
              | ((unsigned)(cy0 * WW + cx1) << 16) | 0x80000000u;
      po23[k] = (unsigned)(cy1 * WW + cx0)
              | ((unsigned)(cy1 * WW + cx1) << 16);
      emask |= 1u << k;
    }
    f16x2 wa = {(f16)g00, (f16)g01};
    f16x2 wb = {(f16)g10, (f16)g11};
    pw01[k] = bcu(wa);
    pw23[k] = bcu(wb);
  }

  f32x4 acc[4];
  #pragma unroll
  for (int nb = 0; nb < 4; ++nb) acc[nb] = (f32x4){0.f, 0.f, 0.f, 0.f};

  // ---- P3: dcn, all 9 taps (R15 structure + R19/R20 lane-exact wtx B) ----
  #define WREAD(ro, pos) (*(const uint4v*)&xwin[((ro) << 7) + ((pos) << 4)])
  if (__ballot(emask != 0) == 0ull) {
    #pragma unroll
    for (int k = 0; k < K2; ++k) {
      unsigned e0 = po01[k], e1 = po23[k];
      int r0 = (int)(e0 & 0x7fffu), r1 = (int)(e0 >> 16);
      int r2 = (int)(e1 & 0x7fffu), r3 = (int)(e1 >> 16);
      int s0 = lh * 2;
      uint4v c0a = WREAD(r0, s0 ^ (r0 & 7));
      uint4v c0b = WREAD(r0, (s0 + 1) ^ (r0 & 7));
      uint4v c1a = WREAD(r1, s0 ^ (r1 & 7));
      uint4v c1b = WREAD(r1, (s0 + 1) ^ (r1 & 7));
      uint4v c2a = WREAD(r2, s0 ^ (r2 & 7));
      uint4v c2b = WREAD(r2, (s0 + 1) ^ (r2 & 7));
      uint4v c3a = WREAD(r3, s0 ^ (r3 & 7));
      uint4v c3b = WREAD(r3, (s0 + 1) ^ (r3 & 7));
      f16x2 wA = bch(pw01[k]), wB = bch(pw23[k]);
      f16x2 p0 = {wA[0], wA[0]}, p1 = {wA[1], wA[1]};
      f16x2 p2 = {wB[0], wB[0]}, p3 = {wB[1], wB[1]};
      uint4v pa, pb2;
      #pragma unroll
      for (int q = 0; q < 4; ++q) {
        f16x2 s  = p0 * bch(c0a[q]) + p1 * bch(c1a[q])
                 + p2 * bch(c2a[q]) + p3 * bch(c3a[q]);
        pa[q] = bcu(s);
        f16x2 s2 = p0 * bch(c0b[q]) + p1 * bch(c1b[q])
                 + p2 * bch(c2b[q]) + p3 * bch(c3b[q]);
        pb2[q] = bcu(s2);
      }
      f16x4 a0 = fq(pa[0],  pa[1]);
      f16x4 a1 = fq(pa[2],  pa[3]);
      f16x4 a2 = fq(pb2[0], pb2[1]);
      f16x4 a3 = fq(pb2[2], pb2[3]);
      const char* wbase = (const char*)wtx + (((size_t)k * 4) * 64 + l) * 32;
      #pragma unroll
      for (int nb = 0; nb < 4; ++nb) {
        const char* wp = wbase + (size_t)nb * (64 * 32);
        uint4v u0 = *(const uint4v*)wp;
        uint4v u1 = *(const uint4v*)(wp + 16);
        acc[nb] = MFMA16(a0, fq(u0[0], u0[1]), acc[nb]);
        acc[nb] = MFMA16(a1, fq(u0[2], u0[3]), acc[nb]);
        acc[nb] = MFMA16(a2, fq(u1[0], u1[1]), acc[nb]);
        acc[nb] = MFMA16(a3, fq(u1[2], u1[3]), acc[nb]);
      }
    }
  } else {
    #pragma unroll
    for (int k = 0; k < K2; ++k) {
      unsigned e0 = po01[k], e1 = po23[k];
      uint4v c0a, c0b, c1a, c1b, c2a, c2b, c3a, c3b;
      if ((int)e0 >= 0) {
        int r0 = (int)(e0 & 0x7fffu), r1 = (int)(e0 >> 16);
        int r2 = (int)(e1 & 0x7fffu), r3 = (int)(e1 >> 16);
        int s0 = lh * 2;
        c0a = WREAD(r0, s0 ^ (r0 & 7));
        c0b = WREAD(r0, (s0 + 1) ^ (r0 & 7));
        c1a = WREAD(r1, s0 ^ (r1 & 7));
        c1b = WREAD(r1, (s0 + 1) ^ (r1 & 7));
        c2a = WREAD(r2, s0 ^ (r2 & 7));
        c2b = WREAD(r2, (s0 + 1) ^ (r2 & 7));
        c3a = WREAD(r3, s0 ^ (r3 & 7));
        c3b = WREAD(r3, (s0 + 1) ^ (r3 & 7));
      } else {
        int i0 = (int)(e0 & 0x7fffu) << 7;
        int i1 = (int)((e0 >> 16) & 0x7fffu) << 7;
        int i2 = (int)(e1 & 0x7fffu) << 7;
        int i3 = (int)((e1 >> 16) & 0x7fffu) << 7;
        c0a = *(const uint4v*)(xb + i0 + cB);
        c0b = *(const uint4v*)(xb + i0 + cB + 16);
        c1a = *(const uint4v*)(xb + i1 + cB);
        c1b = *(const uint4v*)(xb + i1 + cB + 16);
        c2a = *(const uint4v*)(xb + i2 + cB);
        c2b = *(const uint4v*)(xb + i2 + cB + 16);
        c3a = *(const uint4v*)(xb + i3 + cB);
        c3b = *(const uint4v*)(xb + i3 + cB + 16);
      }
      f16x2 wA = bch(pw01[k]), wB = bch(pw23[k]);
      f16x2 p0 = {wA[0], wA[0]}, p1 = {wA[1], wA[1]};
      f16x2 p2 = {wB[0], wB[0]}, p3 = {wB[1], wB[1]};
      uint4v pa, pb2;
      #pragma unroll
      for (int q = 0; q < 4; ++q) {
        f16x2 s  = p0 * bch(c0a[q]) + p1 * bch(c1a[q])
                 + p2 * bch(c2a[q]) + p3 * bch(c3a[q]);
        pa[q] = bcu(s);
        f16x2 s2 = p0 * bch(c0b[q]) + p1 * bch(c1b[q])
                 + p2 * bch(c2b[q]) + p3 * bch(c3b[q]);
        pb2[q] = bcu(s2);
      }
      f16x4 a0 = fq(pa[0],  pa[1]);
      f16x4 a1 = fq(pa[2],  pa[3]);
      f16x4 a2 = fq(pb2[0], pb2[1]);
      f16x4 a3 = fq(pb2[2], pb2[3]);
      const char* wbase = (const char*)wtx + (((size_t)k * 4) * 64 + l) * 32;
      #pragma unroll
      for (int nb = 0; nb < 4; ++nb) {
        const char* wp = wbase + (size_t)nb * (64 * 32);
        uint4v u0 = *(const uint4v*)wp;
        uint4v u1 = *(const uint4v*)(wp + 16);
        acc[nb] = MFMA16(a0, fq(u0[0], u0[1]), acc[nb]);
        acc[nb] = MFMA16(a1, fq(u0[2], u0[3]), acc[nb]);
        acc[nb] = MFMA16(a2, fq(u1[0], u1[1]), acc[nb]);
        acc[nb] = MFMA16(a3, fq(u1[2], u1[3]), acc[nb]);
      }
    }
  }

  // ---- epilogue (R15-verified direct store; pixel runs 4-aligned) ----
  float* ob = out + (size_t)b * OO * HW;
  #pragma unroll
  for (int nb = 0; nb < 4; ++nb) {
    int o = nb * 16 + lr;
    int m = wv * 16 + lh * 4;
    int base2 = hw0 + (m >> 5) * WW + (m & 31);
    *(f32x4*)(ob + (size_t)o * HW + base2) = acc[nb];
  }
}

extern "C" void kernel_launch(void* const* d_in, const int* in_sizes, int n_in,
                              void* d_out, int out_size, void* d_ws, size_t ws_size,
                              hipStream_t stream) {
  const float* x     = (const float*)d_in[0];
  const float* w_off = (const float*)d_in[1];
  const float* b_off = (const float*)d_in[2];
  const float* w_dcn = (const float*)d_in[3];
  float* out = (float*)d_out;

  char* ws = (char*)d_ws;
  unsigned short* xtp  = (unsigned short*)ws;                     // 9,437,184 B
  unsigned short* wtx  = (unsigned short*)(ws + 9437184);         //    73,728 B
  unsigned short* wofx = (unsigned short*)(ws + 9437184 + 73728); //    36,864 B

  transpose_kernel<<<NPIX / 64, 256, 0, stream>>>(x, xtp);
  prep_kernel<<<(36864 + 18432) / 256, 256, 0, stream>>>(w_dcn, w_off, wtx, wofx);
  fused_kernel<<<NPIX / MT, 512, 0, stream>>>(xtp, wofx, b_off, wtx, out);
}

// Round 22
// 45.325 us; speedup vs baseline: 1.3378x; 1.3378x over previous
//
#include <hip/hip_runtime.h>

#define BB 8
#define CC 64
#define HH 96
#define WW 96
#define OO 64
#define KK 3
#define K2 9
#define HW (HH*WW)      // 9216
#define NOFF 18
#define NPIX (BB*HW)    // 73728
#define MT 64           // pixels per fused block: 2 rows x 32 cols (R20-verified)
#define NTILE (HW/MT)   // 144 tiles per image
#define NXCD 8
#define WR 6
#define WC 36
#define NWIN (WR*WC)    // 216 window pixel-rows, 128 B each (seg-swizzled)
#define OSTR 21         // offs row stride (floats)

typedef _Float16 f16;
typedef __attribute__((ext_vector_type(2))) _Float16 f16x2;
typedef __attribute__((ext_vector_type(4))) _Float16 f16x4;
typedef __attribute__((ext_vector_type(4))) float f32x4;
typedef __attribute__((ext_vector_type(2))) unsigned int uint2v;
typedef __attribute__((ext_vector_type(4))) unsigned int uint4v;

#define MFMA16(a,b,c) __builtin_amdgcn_mfma_f32_16x16x16f16(a,b,c,0,0,0)

__device__ __forceinline__ f16x2 bch(unsigned u) { return __builtin_bit_cast(f16x2, u); }
__device__ __forceinline__ unsigned bcu(f16x2 h) { return __builtin_bit_cast(unsigned, h); }
__device__ __forceinline__ f16x4 fq(unsigned a, unsigned b) {
  uint2v u = {a, b};
  return __builtin_bit_cast(f16x4, u);
}
__device__ __forceinline__ f16x4 fq2(uint2v u) { return __builtin_bit_cast(f16x4, u); }
__device__ __forceinline__ int xcd_remap(int bid, int per) {
  return (bid & 7) * per + (bid >> 3);
}

// ---------------- Kernel T: NCHW fp32 -> NHWC f16 (verified R5) -------------
__global__ __launch_bounds__(256) void transpose_kernel(
    const float* __restrict__ x, unsigned short* __restrict__ xt) {
  int t = threadIdx.x;
  int px = xcd_remap(blockIdx.x, NPIX / 64 / NXCD) * 64 + (t & 63);
  int cg = t >> 6;
  int b = px / HW, hw = px % HW;
  const float* xp = x + (size_t)b * CC * HW + (size_t)(cg * 16) * HW + hw;
  f16 r[16];
  #pragma unroll
  for (int i = 0; i < 16; ++i) r[i] = (f16)xp[i * HW];
  uint4v v0, v1;
  #pragma unroll
  for (int q = 0; q < 4; ++q) {
    f16x2 a = {r[q*2], r[q*2+1]};       v0[q] = bcu(a);
    f16x2 bq = {r[8+q*2], r[8+q*2+1]};  v1[q] = bcu(bq);
  }
  uint4v* dst = (uint4v*)(xt + (size_t)px * CC + cg * 16);
  dst[0] = v0; dst[1] = v1;
}

// ------- Kernel P: merged weight prep (R21-verified; layouts R19/R20) -------
// wtx[k][nb][l][16ch]: c = 16*(l>>4)+e, o = nb*16+(l&15)
// wofx[kt][n][q][l][4ch]: c = 16q+4*(l>>4)+e, j = n*16+(l&15); j>=18 -> 0
__global__ void prep_kernel(const float* __restrict__ w_dcn,
                            const float* __restrict__ w_off,
                            unsigned short* __restrict__ wtx,
                            unsigned short* __restrict__ wofx) {
  int idx = blockIdx.x * 256 + threadIdx.x;   // 36864 + 18432 = 55296
  if (idx < 36864) {
    int e = idx & 15;
    int l = (idx >> 4) & 63;
    int nb = (idx >> 10) & 3;
    int k = idx >> 12;
    int c = 16 * (l >> 4) + e;
    int o = nb * 16 + (l & 15);
    f16 h = (f16)w_dcn[(o * CC + c) * K2 + k];
    wtx[idx] = __builtin_bit_cast(unsigned short, h);
  } else {
    int i2 = idx - 36864;
    int e = i2 & 3;
    int l = (i2 >> 2) & 63;
    int q = (i2 >> 8) & 3;
    int n = (i2 >> 10) & 1;
    int kt = i2 >> 11;
    int c = q * 16 + 4 * (l >> 4) + e;
    int j = n * 16 + (l & 15);
    f16 h = (f16)((j < NOFF) ? w_off[(j * CC + c) * K2 + kt] : 0.f);
    wofx[i2] = __builtin_bit_cast(unsigned short, h);
  }
}

// ---------------- Kernel F: fused offconv(MFMA) + dcn(MFMA) — R20 exact -----
#define XWIN_OFF 0
#define OFFS_OFF 27648
#define ACCX_OFF 0        // aliases xwin (dead after P3)
#define SMEM_SZ  33024

__global__ __launch_bounds__(512, 4) void fused_kernel(
    const unsigned short* __restrict__ xt,    // [B][HW][C] f16
    const unsigned short* __restrict__ wofx,  // [K2][2][4][64][4] f16
    const float* __restrict__ b_off,          // [18] fp32
    const unsigned short* __restrict__ wtx,   // [K2][4][64][16] f16
    float* __restrict__ out) {
  __shared__ __align__(16) char smem[SMEM_SZ];
  char* xwin = smem + XWIN_OFF;              // 216 x 128 B, seg-swizzled
  float* offs = (float*)(smem + OFFS_OFF);   // [64][21]
  float* accx = (float*)(smem + ACCX_OFF);   // [64 o][68 px] (aliases xwin)

  int t = threadIdx.x;
  int blk = xcd_remap(blockIdx.x, NPIX / MT / NXCD);
  int b = blk / NTILE;
  int ti = blk % NTILE;
  int tr = ti / 3, tc = ti % 3;
  int h0 = tr * 2, w0 = tc * 32;
  int hw0 = h0 * WW + w0;

  const char* xb = (const char*)(xt + (size_t)b * HW * CC);

  // ---- P0: stage window, seg-swizzled, ZERO-fill out-of-image (R18/R20) ----
  #pragma unroll
  for (int r = 0; r < 4; ++r) {
    int d = r * 512 + t;                     // 16-B chunk id, 1728 total
    if (d < NWIN * 8) {
      int row = d >> 3, sg = d & 7;
      int wr_ = row / WC, wc_ = row - wr_ * WC;
      int gy = h0 - 2 + wr_;
      int gx = w0 - 2 + wc_;
      uint4v v = (uint4v){0u, 0u, 0u, 0u};
      if (((unsigned)gy < HH) && ((unsigned)gx < WW))
        v = *(const uint4v*)(xb + (size_t)((gy * WW + gx) << 7) + (sg << 4));
      *(uint4v*)&xwin[row * 128 + ((sg ^ (row & 7)) << 4)] = v;
    }
  }
  __syncthreads();

  // wave geometry (verified R9/R12)
  int wv = t >> 6;
  int l  = t & 63;
  int lr = l & 15, lh = l >> 4;

  // ---- P1: offset conv via MFMA (R20-verified; wofx B coalesced) ----
  {
    int m = wv & 3, n = wv >> 2;             // 4 pixel-tiles x 2 j-tiles
    int p = m * 16 + lr;
    int prow = ((p >> 5) + 1) * WC + (p & 31) + 1;  // window row at ky=kx=0
    f32x4 accO = (f32x4){0.f, 0.f, 0.f, 0.f};
    #pragma unroll
    for (int kt = 0; kt < K2; ++kt) {
      int wrow = prow + (kt / 3) * WC + (kt % 3);
      int rs = wrow & 7;
      const char* bp = (const char*)wofx + (((size_t)(kt * 2 + n) * 4) * 64 + l) * 8;
      #pragma unroll
      for (int q = 0; q < 4; ++q) {
        uint2v a2 = *(const uint2v*)&xwin[wrow * 128
                      + ((((q << 1) + (lh >> 1)) ^ rs) << 4) + ((lh & 1) << 3)];
        uint2v b2 = *(const uint2v*)(bp + (size_t)q * (64 * 8));
        accO = MFMA16(fq2(a2), fq2(b2), accO);
      }
    }
    int j = n * 16 + lr;
    if (j < NOFF) {
      float bj = b_off[j];
      #pragma unroll
      for (int r = 0; r < 4; ++r) {
        int px = m * 16 + lh * 4 + r;        // D row = pixel (R9 map)
        offs[px * OSTR + j] = accO[r] + bj;
      }
    }
  }
  __syncthreads();

  // ---- P2: per-lane params for this group's taps (R15/R17/R20 math) ----
  int grp = wv >> 2;
  int base = grp * 5;                  // g0: taps 0..4, g1: taps 5..8
  int cnt  = 5 - grp;
  int Ra = (wv & 3) * 16 + lr;
  int hpix = h0 + (Ra >> 5), wpix = w0 + (Ra & 31);
  int cB = lh * 32;

  unsigned po01[5], po23[5], pw01[5], pw23[5];
  unsigned emask = 0;
  #pragma unroll
  for (int i = 0; i < 5; ++i) {
    po01[i] = 0; po23[i] = 0; pw01[i] = 0; pw23[i] = 0;
    if (i < cnt) {
      int kt = base + i;
      int ky = kt / 3, kx = kt % 3;
      float py = offs[Ra * OSTR + 2 * kt]     + (float)(hpix - 1 + ky);
      float px = offs[Ra * OSTR + 2 * kt + 1] + (float)(wpix - 1 + kx);
      float y0f = floorf(py), x0f = floorf(px);
      float wy = py - y0f, wx = px - x0f;
      int y0 = (int)y0f, x0 = (int)x0f;
      int y1 = y0 + 1, x1 = x0 + 1;
      bool vy0 = (unsigned)y0 < HH, vy1 = (unsigned)y1 < HH;
      bool vx0 = (unsigned)x0 < WW, vx1 = (unsigned)x1 < WW;
      int cy0 = min(max(y0, 0), HH - 1), cy1 = min(max(y1, 0), HH - 1);
      int cx0 = min(max(x0, 0), WW - 1), cx1 = min(max(x1, 0), WW - 1);
      float g00 = (1.f - wy) * (1.f - wx) * ((vy0 && vx0) ? 1.f : 0.f);
      float g01 = (1.f - wy) * wx         * ((vy0 && vx1) ? 1.f : 0.f);
      float g10 = wy * (1.f - wx)         * ((vy1 && vx0) ? 1.f : 0.f);
      float g11 = wy * wx                 * ((vy1 && vx1) ? 1.f : 0.f);
      int ry0 = cy0 - (h0 - 2), ry1 = cy1 - (h0 - 2);
      int rx0 = cx0 - (w0 - 2), rx1 = cx1 - (w0 - 2);
      bool inw = ((unsigned)ry0 < WR) && ((unsigned)ry1 < WR) &&
                 ((unsigned)rx0 < WC) && ((unsigned)rx1 < WC);
      if (inw) {
        po01[i] = (unsigned)((ry0 * WC + rx0) << 7)
                | ((unsigned)((ry0 * WC + rx1) << 7) << 16);
        po23[i] = (unsigned)((ry1 * WC + rx0) << 7)
                | ((unsigned)((ry1 * WC + rx1) << 7) << 16);
      } else {
        po01[i] = (unsigned)(cy0 * WW + cx0)
                | ((unsigned)(cy0 * WW + cx1) << 16) | 0x80000000u;
        po23[i] = (unsigned)(cy1 * WW + cx0)
                | ((unsigned)(cy1 * WW + cx1) << 16);
        emask |= 1u << i;
      }
      f16x2 wa = {(f16)g00, (f16)g01};
      f16x2 wb = {(f16)g10, (f16)g11};
      pw01[i] = bcu(wa);
      pw23[i] = bcu(wb);
    }
  }

  f32x4 acc[4];
  #pragma unroll
  for (int nb = 0; nb < 4; ++nb) acc[nb] = (f32x4){0.f, 0.f, 0.f, 0.f};

  // ---- P3: dcn taps (R19/R20-verified: blend/MFMA + lane-exact wtx B) ----
  #define WREAD(bo, pos) (*(const uint4v*)&xwin[(bo) + ((pos) << 4)])
  if (__ballot(emask != 0) == 0ull) {
    #pragma unroll
    for (int i = 0; i < 5; ++i) {
      if (i < cnt) {
        unsigned e0 = po01[i], e1 = po23[i];
        int i0 = (int)(e0 & 0xffffu), i1 = (int)(e0 >> 16);
        int i2 = (int)(e1 & 0xffffu), i3 = (int)(e1 >> 16);
        int s0 = lh * 2;
        uint4v c0a = WREAD(i0, s0 ^ ((i0 >> 7) & 7));
        uint4v c0b = WREAD(i0, (s0 + 1) ^ ((i0 >> 7) & 7));
        uint4v c1a = WREAD(i1, s0 ^ ((i1 >> 7) & 7));
        uint4v c1b = WREAD(i1, (s0 + 1) ^ ((i1 >> 7) & 7));
        uint4v c2a = WREAD(i2, s0 ^ ((i2 >> 7) & 7));
        uint4v c2b = WREAD(i2, (s0 + 1) ^ ((i2 >> 7) & 7));
        uint4v c3a = WREAD(i3, s0 ^ ((i3 >> 7) & 7));
        uint4v c3b = WREAD(i3, (s0 + 1) ^ ((i3 >> 7) & 7));
        f16x2 wA = bch(pw01[i]), wB = bch(pw23[i]);
        f16x2 p0 = {wA[0], wA[0]}, p1 = {wA[1], wA[1]};
        f16x2 p2 = {wB[0], wB[0]}, p3 = {wB[1], wB[1]};
        uint4v pa, pb2;
        #pragma unroll
        for (int q = 0; q < 4; ++q) {
          f16x2 s  = p0 * bch(c0a[q]) + p1 * bch(c1a[q])
                   + p2 * bch(c2a[q]) + p3 * bch(c3a[q]);
          pa[q] = bcu(s);
          f16x2 s2 = p0 * bch(c0b[q]) + p1 * bch(c1b[q])
                   + p2 * bch(c2b[q]) + p3 * bch(c3b[q]);
          pb2[q] = bcu(s2);
        }
        f16x4 a0 = fq(pa[0],  pa[1]);
        f16x4 a1 = fq(pa[2],  pa[3]);
        f16x4 a2 = fq(pb2[0], pb2[1]);
        f16x4 a3 = fq(pb2[2], pb2[3]);
        const char* wbase = (const char*)wtx
                          + (((size_t)(base + i) * 4) * 64 + l) * 32;
        #pragma unroll
        for (int nb = 0; nb < 4; ++nb) {
          const char* wp = wbase + (size_t)nb * (64 * 32);
          uint4v u0 = *(const uint4v*)wp;
          uint4v u1 = *(const uint4v*)(wp + 16);
          acc[nb] = MFMA16(a0, fq(u0[0], u0[1]), acc[nb]);
          acc[nb] = MFMA16(a1, fq(u0[2], u0[3]), acc[nb]);
          acc[nb] = MFMA16(a2, fq(u1[0], u1[1]), acc[nb]);
          acc[nb] = MFMA16(a3, fq(u1[2], u1[3]), acc[nb]);
        }
      }
    }
  } else {
    #pragma unroll
    for (int i = 0; i < 5; ++i) {
      if (i < cnt) {
        unsigned e0 = po01[i], e1 = po23[i];
        uint4v c0a, c0b, c1a, c1b, c2a, c2b, c3a, c3b;
        if ((int)e0 >= 0) {
          int i0 = (int)(e0 & 0xffffu), i1 = (int)(e0 >> 16);
          int i2 = (int)(e1 & 0xffffu), i3 = (int)(e1 >> 16);
          int s0 = lh * 2;
          c0a = WREAD(i0, s0 ^ ((i0 >> 7) & 7));
          c0b = WREAD(i0, (s0 + 1) ^ ((i0 >> 7) & 7));
          c1a = WREAD(i1, s0 ^ ((i1 >> 7) & 7));
          c1b = WREAD(i1, (s0 + 1) ^ ((i1 >> 7) & 7));
          c2a = WREAD(i2, s0 ^ ((i2 >> 7) & 7));
          c2b = WREAD(i2, (s0 + 1) ^ ((i2 >> 7) & 7));
          c3a = WREAD(i3, s0 ^ ((i3 >> 7) & 7));
          c3b = WREAD(i3, (s0 + 1) ^ ((i3 >> 7) & 7));
        } else {
          int i0 = (int)(e0 & 0x7fffu) << 7;
          int i1 = (int)((e0 >> 16) & 0x7fffu) << 7;
          int i2 = (int)(e1 & 0x7fffu) << 7;
          int i3 = (int)((e1 >> 16) & 0x7fffu) << 7;
          c0a = *(const uint4v*)(xb + i0 + cB);
          c0b = *(const uint4v*)(xb + i0 + cB + 16);
          c1a = *(const uint4v*)(xb + i1 + cB);
          c1b = *(const uint4v*)(xb + i1 + cB + 16);
          c2a = *(const uint4v*)(xb + i2 + cB);
          c2b = *(const uint4v*)(xb + i2 + cB + 16);
          c3a = *(const uint4v*)(xb + i3 + cB);
          c3b = *(const uint4v*)(xb + i3 + cB + 16);
        }
        f16x2 wA = bch(pw01[i]), wB = bch(pw23[i]);
        f16x2 p0 = {wA[0], wA[0]}, p1 = {wA[1], wA[1]};
        f16x2 p2 = {wB[0], wB[0]}, p3 = {wB[1], wB[1]};
        uint4v pa, pb2;
        #pragma unroll
        for (int q = 0; q < 4; ++q) {
          f16x2 s  = p0 * bch(c0a[q]) + p1 * bch(c1a[q])
                   + p2 * bch(c2a[q]) + p3 * bch(c3a[q]);
          pa[q] = bcu(s);
          f16x2 s2 = p0 * bch(c0b[q]) + p1 * bch(c1b[q])
                   + p2 * bch(c2b[q]) + p3 * bch(c3b[q]);
          pb2[q] = bcu(s2);
        }
        f16x4 a0 = fq(pa[0],  pa[1]);
        f16x4 a1 = fq(pa[2],  pa[3]);
        f16x4 a2 = fq(pb2[0], pb2[1]);
        f16x4 a3 = fq(pb2[2], pb2[3]);
        const char* wbase = (const char*)wtx
                          + (((size_t)(base + i) * 4) * 64 + l) * 32;
        #pragma unroll
        for (int nb = 0; nb < 4; ++nb) {
          const char* wp = wbase + (size_t)nb * (64 * 32);
          uint4v u0 = *(const uint4v*)wp;
          uint4v u1 = *(const uint4v*)(wp + 16);
          acc[nb] = MFMA16(a0, fq(u0[0], u0[1]), acc[nb]);
          acc[nb] = MFMA16(a1, fq(u0[2], u0[3]), acc[nb]);
          acc[nb] = MFMA16(a2, fq(u1[0], u1[1]), acc[nb]);
          acc[nb] = MFMA16(a3, fq(u1[2], u1[3]), acc[nb]);
        }
      }
    }
  }
  __syncthreads();   // xwin dead; accx (alias) exchange

  // ---- P4: group1 -> accx, group0 adds + stores (verified R17..R20) ----
  if (grp == 1) {
    #pragma unroll
    for (int nb = 0; nb < 4; ++nb)
      *(f32x4*)&accx[(nb * 16 + lr) * 68 + (wv & 3) * 16 + lh * 4] = acc[nb];
  }
  __syncthreads();
  if (grp == 0) {
    float* ob = out + (size_t)b * OO * HW;
    #pragma unroll
    for (int nb = 0; nb < 4; ++nb) {
      f32x4 other = *(const f32x4*)&accx[(nb * 16 + lr) * 68 + (wv & 3) * 16 + lh * 4];
      f32x4 v = acc[nb] + other;
      int o = nb * 16 + lr;
      int m = (wv & 3) * 16 + lh * 4;
      int base2 = hw0 + (m >> 5) * WW + (m & 31);
      *(f32x4*)(ob + (size_t)o * HW + base2) = v;
    }
  }
}

extern "C" void kernel_launch(void* const* d_in, const int* in_sizes, int n_in,
                              void* d_out, int out_size, void* d_ws, size_t ws_size,
                              hipStream_t stream) {
  const float* x     = (const float*)d_in[0];
  const float* w_off = (const float*)d_in[1];
  const float* b_off = (const float*)d_in[2];
  const float* w_dcn = (const float*)d_in[3];
  float* out = (float*)d_out;

  char* ws = (char*)d_ws;
  unsigned short* xtp  = (unsigned short*)ws;                     // 9,437,184 B
  unsigned short* wtx  = (unsigned short*)(ws + 9437184);         //    73,728 B
  unsigned short* wofx = (unsigned short*)(ws + 9437184 + 73728); //    36,864 B

  transpose_kernel<<<NPIX / 64, 256, 0, stream>>>(x, xtp);
  prep_kernel<<<(36864 + 18432) / 256, 256, 0, stream>>>(w_dcn, w_off, wtx, wofx);
  fused_kernel<<<NPIX / MT, 512, 0, stream>>>(xtp, wofx, b_off, wtx, out);
}

// Round 23
// 42.026 us; speedup vs baseline: 1.4428x; 1.0785x over previous
//
#include <hip/hip_runtime.h>

#define BB 8
#define CC 64
#define HH 96
#define WW 96
#define OO 64
#define KK 3
#define K2 9
#define HW (HH*WW)      // 9216
#define NOFF 18
#define NPIX (BB*HW)    // 73728
#define MT 64           // pixels per fused block: 2 rows x 32 cols (R20-verified)
#define NTILE (HW/MT)   // 144 tiles per image
#define NXCD 8
#define WR 6
#define WC 36
#define NWIN (WR*WC)    // 216 window pixel-rows, 128 B each (seg-swizzled)
#define OSTR 21         // offs row stride (floats)

typedef _Float16 f16;
typedef __attribute__((ext_vector_type(2))) _Float16 f16x2;
typedef __attribute__((ext_vector_type(4))) _Float16 f16x4;
typedef __attribute__((ext_vector_type(4))) float f32x4;
typedef __attribute__((ext_vector_type(2))) unsigned int uint2v;
typedef __attribute__((ext_vector_type(4))) unsigned int uint4v;

#define MFMA16(a,b,c) __builtin_amdgcn_mfma_f32_16x16x16f16(a,b,c,0,0,0)

typedef const unsigned int __attribute__((address_space(1))) gau32;
typedef unsigned int __attribute__((address_space(3))) lau32;

__device__ __forceinline__ f16x2 bch(unsigned u) { return __builtin_bit_cast(f16x2, u); }
__device__ __forceinline__ unsigned bcu(f16x2 h) { return __builtin_bit_cast(unsigned, h); }
__device__ __forceinline__ f16x4 fq(unsigned a, unsigned b) {
  uint2v u = {a, b};
  return __builtin_bit_cast(f16x4, u);
}
__device__ __forceinline__ f16x4 fq2(uint2v u) { return __builtin_bit_cast(f16x4, u); }
__device__ __forceinline__ int xcd_remap(int bid, int per) {
  return (bid & 7) * per + (bid >> 3);
}

// ---------------- Kernel T: NCHW fp32 -> NHWC f16 (verified R5) -------------
__global__ __launch_bounds__(256) void transpose_kernel(
    const float* __restrict__ x, unsigned short* __restrict__ xt) {
  int t = threadIdx.x;
  int px = xcd_remap(blockIdx.x, NPIX / 64 / NXCD) * 64 + (t & 63);
  int cg = t >> 6;
  int b = px / HW, hw = px % HW;
  const float* xp = x + (size_t)b * CC * HW + (size_t)(cg * 16) * HW + hw;
  f16 r[16];
  #pragma unroll
  for (int i = 0; i < 16; ++i) r[i] = (f16)xp[i * HW];
  uint4v v0, v1;
  #pragma unroll
  for (int q = 0; q < 4; ++q) {
    f16x2 a = {r[q*2], r[q*2+1]};       v0[q] = bcu(a);
    f16x2 bq = {r[8+q*2], r[8+q*2+1]};  v1[q] = bcu(bq);
  }
  uint4v* dst = (uint4v*)(xt + (size_t)px * CC + cg * 16);
  dst[0] = v0; dst[1] = v1;
}

// ------- Kernel P: merged weight prep + zero page ---------------------------
// wtx[k][nb][l][16ch]: c = 16*(l>>4)+e, o = nb*16+(l&15)          (R19-verified)
// wofx[kt][n][l][16]: m = q*4+e -> c = 16q+4*(l>>4)+e, j = n*16+(l&15)
//   (same kappa/values as R20-verified wofx, relocated for b128 reads; j>=18->0)
__global__ void prep_kernel(const float* __restrict__ w_dcn,
                            const float* __restrict__ w_off,
                            unsigned short* __restrict__ wtx,
                            unsigned short* __restrict__ wofx,
                            unsigned short* __restrict__ zp) {
  int idx = blockIdx.x * 256 + threadIdx.x;   // 36864 + 18432 = 55296
  if (idx < 64) zp[idx] = 0;                  // 128-B zero page
  if (idx < 36864) {
    int e = idx & 15;
    int l = (idx >> 4) & 63;
    int nb = (idx >> 10) & 3;
    int k = idx >> 12;
    int c = 16 * (l >> 4) + e;
    int o = nb * 16 + (l & 15);
    f16 h = (f16)w_dcn[(o * CC + c) * K2 + k];
    wtx[idx] = __builtin_bit_cast(unsigned short, h);
  } else {
    int i2 = idx - 36864;
    int m = i2 & 15;                          // m = q*4 + e
    int l = (i2 >> 4) & 63;
    int n = (i2 >> 10) & 1;
    int kt = i2 >> 11;
    int q = m >> 2, e = m & 3;
    int c = q * 16 + 4 * (l >> 4) + e;
    int j = n * 16 + (l & 15);
    f16 h = (f16)((j < NOFF) ? w_off[(j * CC + c) * K2 + kt] : 0.f);
    wofx[i2] = __builtin_bit_cast(unsigned short, h);
  }
}

// ---------------- Kernel F: fused offconv(MFMA) + dcn(MFMA) — R22 base ------
#define XWIN_OFF 0
#define OFFS_OFF 27648
#define ACCX_OFF 0        // aliases xwin (dead after P3)
#define SMEM_SZ  33024

__global__ __launch_bounds__(512, 4) void fused_kernel(
    const unsigned short* __restrict__ xt,    // [B][HW][C] f16
    const unsigned short* __restrict__ wofx,  // [K2][2][64][16] f16
    const float* __restrict__ b_off,          // [18] fp32
    const unsigned short* __restrict__ wtx,   // [K2][4][64][16] f16
    const unsigned short* __restrict__ zp,    // 128-B zero page
    float* __restrict__ out) {
  __shared__ __align__(16) char smem[SMEM_SZ];
  char* xwin = smem + XWIN_OFF;              // 216 x 128 B, seg-swizzled
  float* offs = (float*)(smem + OFFS_OFF);   // [64][21]
  float* accx = (float*)(smem + ACCX_OFF);   // [64 o][68 px] (aliases xwin)

  int t = threadIdx.x;
  int blk = xcd_remap(blockIdx.x, NPIX / MT / NXCD);
  int b = blk / NTILE;
  int ti = blk % NTILE;
  int tr = ti / 3, tc = ti % 3;
  int h0 = tr * 2, w0 = tc * 32;
  int hw0 = h0 * WW + w0;

  const char* xb = (const char*)(xt + (size_t)b * HW * CC);

  // ---- P0: stage window via global_load_lds (rule #21: linear LDS dest,
  // swizzle folded into per-lane SOURCE; OOB rows read the zero page) ----
  #pragma unroll
  for (int r = 0; r < 4; ++r) {
    int d = r * 512 + t;                     // 16-B chunk id, 1728 = 27 waves
    if (d < NWIN * 8) {                      // wave-uniform (27 full waves)
      int row = d >> 3, pos = d & 7;
      int wr_ = row / WC, wc_ = row - wr_ * WC;
      int gy = h0 - 2 + wr_;
      int gx = w0 - 2 + wc_;
      int sg = pos ^ (row & 7);              // content seg for this slot
      const char* src = (((unsigned)gy < HH) && ((unsigned)gx < WW))
          ? xb + (size_t)((gy * WW + gx) << 7) + (sg << 4)
          : (const char*)zp + (sg << 4);
      __builtin_amdgcn_global_load_lds((gau32*)src, (lau32*)(xwin + d * 16),
                                       16, 0, 0);
    }
  }
  __syncthreads();   // compiler drains vmcnt(0) before barrier -> loads landed

  // wave geometry (verified R9/R12)
  int wv = t >> 6;
  int l  = t & 63;
  int lr = l & 15, lh = l >> 4;

  // ---- P1: offset conv via MFMA (R20/R22 math; wofx b128 reads) ----
  {
    int m = wv & 3, n = wv >> 2;             // 4 pixel-tiles x 2 j-tiles
    int p = m * 16 + lr;
    int prow = ((p >> 5) + 1) * WC + (p & 31) + 1;  // window row at ky=kx=0
    f32x4 accO = (f32x4){0.f, 0.f, 0.f, 0.f};
    __builtin_amdgcn_s_setprio(1);
    #pragma unroll
    for (int kt = 0; kt < K2; ++kt) {
      int wrow = prow + (kt / 3) * WC + (kt % 3);
      int rs = wrow & 7;
      const char* bp = (const char*)wofx + (((size_t)(kt * 2 + n)) * 64 + l) * 32;
      uint4v bw0 = *(const uint4v*)bp;        // q=0 (words 0,1), q=1 (2,3)
      uint4v bw1 = *(const uint4v*)(bp + 16); // q=2, q=3
      #pragma unroll
      for (int q = 0; q < 4; ++q) {
        uint2v a2 = *(const uint2v*)&xwin[wrow * 128
                      + ((((q << 1) + (lh >> 1)) ^ rs) << 4) + ((lh & 1) << 3)];
        uint2v b2;
        if (q == 0)      { b2[0] = bw0[0]; b2[1] = bw0[1]; }
        else if (q == 1) { b2[0] = bw0[2]; b2[1] = bw0[3]; }
        else if (q == 2) { b2[0] = bw1[0]; b2[1] = bw1[1]; }
        else             { b2[0] = bw1[2]; b2[1] = bw1[3]; }
        accO = MFMA16(fq2(a2), fq2(b2), accO);
      }
    }
    __builtin_amdgcn_s_setprio(0);
    int j = n * 16 + lr;
    if (j < NOFF) {
      float bj = b_off[j];
      #pragma unroll
      for (int r = 0; r < 4; ++r) {
        int px = m * 16 + lh * 4 + r;        // D row = pixel (R9 map)
        offs[px * OSTR + j] = accO[r] + bj;
      }
    }
  }
  __syncthreads();

  // ---- P2: per-lane params for this group's taps (R15/R17/R20 math) ----
  int grp = wv >> 2;
  int base = grp * 5;                  // g0: taps 0..4, g1: taps 5..8
  int cnt  = 5 - grp;
  int Ra = (wv & 3) * 16 + lr;
  int hpix = h0 + (Ra >> 5), wpix = w0 + (Ra & 31);
  int cB = lh * 32;

  unsigned po01[5], po23[5], pw01[5], pw23[5];
  unsigned emask = 0;
  #pragma unroll
  for (int i = 0; i < 5; ++i) {
    po01[i] = 0; po23[i] = 0; pw01[i] = 0; pw23[i] = 0;
    if (i < cnt) {
      int kt = base + i;
      int ky = kt / 3, kx = kt % 3;
      float py = offs[Ra * OSTR + 2 * kt]     + (float)(hpix - 1 + ky);
      float px = offs[Ra * OSTR + 2 * kt + 1] + (float)(wpix - 1 + kx);
      float y0f = floorf(py), x0f = floorf(px);
      float wy = py - y0f, wx = px - x0f;
      int y0 = (int)y0f, x0 = (int)x0f;
      int y1 = y0 + 1, x1 = x0 + 1;
      bool vy0 = (unsigned)y0 < HH, vy1 = (unsigned)y1 < HH;
      bool vx0 = (unsigned)x0 < WW, vx1 = (unsigned)x1 < WW;
      int cy0 = min(max(y0, 0), HH - 1), cy1 = min(max(y1, 0), HH - 1);
      int cx0 = min(max(x0, 0), WW - 1), cx1 = min(max(x1, 0), WW - 1);
      float g00 = (1.f - wy) * (1.f - wx) * ((vy0 && vx0) ? 1.f : 0.f);
      float g01 = (1.f - wy) * wx         * ((vy0 && vx1) ? 1.f : 0.f);
      float g10 = wy * (1.f - wx)         * ((vy1 && vx0) ? 1.f : 0.f);
      float g11 = wy * wx                 * ((vy1 && vx1) ? 1.f : 0.f);
      int ry0 = cy0 - (h0 - 2), ry1 = cy1 - (h0 - 2);
      int rx0 = cx0 - (w0 - 2), rx1 = cx1 - (w0 - 2);
      bool inw = ((unsigned)ry0 < WR) && ((unsigned)ry1 < WR) &&
                 ((unsigned)rx0 < WC) && ((unsigned)rx1 < WC);
      if (inw) {
        po01[i] = (unsigned)((ry0 * WC + rx0) << 7)
                | ((unsigned)((ry0 * WC + rx1) << 7) << 16);
        po23[i] = (unsigned)((ry1 * WC + rx0) << 7)
                | ((unsigned)((ry1 * WC + rx1) << 7) << 16);
      } else {
        po01[i] = (unsigned)(cy0 * WW + cx0)
                | ((unsigned)(cy0 * WW + cx1) << 16) | 0x80000000u;
        po23[i] = (unsigned)(cy1 * WW + cx0)
                | ((unsigned)(cy1 * WW + cx1) << 16);
        emask |= 1u << i;
      }
      f16x2 wa = {(f16)g00, (f16)g01};
      f16x2 wb = {(f16)g10, (f16)g11};
      pw01[i] = bcu(wa);
      pw23[i] = bcu(wb);
    }
  }

  f32x4 acc[4];
  #pragma unroll
  for (int nb = 0; nb < 4; ++nb) acc[nb] = (f32x4){0.f, 0.f, 0.f, 0.f};

  // ---- P3: dcn taps (R19/R20/R22-verified: blend/MFMA + lane-exact wtx) ----
  #define WREAD(bo, pos) (*(const uint4v*)&xwin[(bo) + ((pos) << 4)])
  if (__ballot(emask != 0) == 0ull) {
    #pragma unroll
    for (int i = 0; i < 5; ++i) {
      if (i < cnt) {
        unsigned e0 = po01[i], e1 = po23[i];
        int i0 = (int)(e0 & 0xffffu), i1 = (int)(e0 >> 16);
        int i2 = (int)(e1 & 0xffffu), i3 = (int)(e1 >> 16);
        int s0 = lh * 2;
        uint4v c0a = WREAD(i0, s0 ^ ((i0 >> 7) & 7));
        uint4v c0b = WREAD(i0, (s0 + 1) ^ ((i0 >> 7) & 7));
        uint4v c1a = WREAD(i1, s0 ^ ((i1 >> 7) & 7));
        uint4v c1b = WREAD(i1, (s0 + 1) ^ ((i1 >> 7) & 7));
        uint4v c2a = WREAD(i2, s0 ^ ((i2 >> 7) & 7));
        uint4v c2b = WREAD(i2, (s0 + 1) ^ ((i2 >> 7) & 7));
        uint4v c3a = WREAD(i3, s0 ^ ((i3 >> 7) & 7));
        uint4v c3b = WREAD(i3, (s0 + 1) ^ ((i3 >> 7) & 7));
        f16x2 wA = bch(pw01[i]), wB = bch(pw23[i]);
        f16x2 p0 = {wA[0], wA[0]}, p1 = {wA[1], wA[1]};
        f16x2 p2 = {wB[0], wB[0]}, p3 = {wB[1], wB[1]};
        uint4v pa, pb2;
        #pragma unroll
        for (int q = 0; q < 4; ++q) {
          f16x2 s  = p0 * bch(c0a[q]) + p1 * bch(c1a[q])
                   + p2 * bch(c2a[q]) + p3 * bch(c3a[q]);
          pa[q] = bcu(s);
          f16x2 s2 = p0 * bch(c0b[q]) + p1 * bch(c1b[q])
                   + p2 * bch(c2b[q]) + p3 * bch(c3b[q]);
          pb2[q] = bcu(s2);
        }
        f16x4 a0 = fq(pa[0],  pa[1]);
        f16x4 a1 = fq(pa[2],  pa[3]);
        f16x4 a2 = fq(pb2[0], pb2[1]);
        f16x4 a3 = fq(pb2[2], pb2[3]);
        const char* wbase = (const char*)wtx
                          + (((size_t)(base + i) * 4) * 64 + l) * 32;
        __builtin_amdgcn_s_setprio(1);
        #pragma unroll
        for (int nb = 0; nb < 4; ++nb) {
          const char* wp = wbase + (size_t)nb * (64 * 32);
          uint4v u0 = *(const uint4v*)wp;
          uint4v u1 = *(const uint4v*)(wp + 16);
          acc[nb] = MFMA16(a0, fq(u0[0], u0[1]), acc[nb]);
          acc[nb] = MFMA16(a1, fq(u0[2], u0[3]), acc[nb]);
          acc[nb] = MFMA16(a2, fq(u1[0], u1[1]), acc[nb]);
          acc[nb] = MFMA16(a3, fq(u1[2], u1[3]), acc[nb]);
        }
        __builtin_amdgcn_s_setprio(0);
      }
    }
  } else {
    #pragma unroll
    for (int i = 0; i < 5; ++i) {
      if (i < cnt) {
        unsigned e0 = po01[i], e1 = po23[i];
        uint4v c0a, c0b, c1a, c1b, c2a, c2b, c3a, c3b;
        if ((int)e0 >= 0) {
          int i0 = (int)(e0 & 0xffffu), i1 = (int)(e0 >> 16);
          int i2 = (int)(e1 & 0xffffu), i3 = (int)(e1 >> 16);
          int s0 = lh * 2;
          c0a = WREAD(i0, s0 ^ ((i0 >> 7) & 7));
          c0b = WREAD(i0, (s0 + 1) ^ ((i0 >> 7) & 7));
          c1a = WREAD(i1, s0 ^ ((i1 >> 7) & 7));
          c1b = WREAD(i1, (s0 + 1) ^ ((i1 >> 7) & 7));
          c2a = WREAD(i2, s0 ^ ((i2 >> 7) & 7));
          c2b = WREAD(i2, (s0 + 1) ^ ((i2 >> 7) & 7));
          c3a = WREAD(i3, s0 ^ ((i3 >> 7) & 7));
          c3b = WREAD(i3, (s0 + 1) ^ ((i3 >> 7) & 7));
        } else {
          int i0 = (int)(e0 & 0x7fffu) << 7;
          int i1 = (int)((e0 >> 16) & 0x7fffu) << 7;
          int i2 = (int)(e1 & 0x7fffu) << 7;
          int i3 = (int)((e1 >> 16) & 0x7fffu) << 7;
          c0a = *(const uint4v*)(xb + i0 + cB);
          c0b = *(const uint4v*)(xb + i0 + cB + 16);
          c1a = *(const uint4v*)(xb + i1 + cB);
          c1b = *(const uint4v*)(xb + i1 + cB + 16);
          c2a = *(const uint4v*)(xb + i2 + cB);
          c2b = *(const uint4v*)(xb + i2 + cB + 16);
          c3a = *(const uint4v*)(xb + i3 + cB);
          c3b = *(const uint4v*)(xb + i3 + cB + 16);
        }
        f16x2 wA = bch(pw01[i]), wB = bch(pw23[i]);
        f16x2 p0 = {wA[0], wA[0]}, p1 = {wA[1], wA[1]};
        f16x2 p2 = {wB[0], wB[0]}, p3 = {wB[1], wB[1]};
        uint4v pa, pb2;
        #pragma unroll
        for (int q = 0; q < 4; ++q) {
          f16x2 s  = p0 * bch(c0a[q]) + p1 * bch(c1a[q])
                   + p2 * bch(c2a[q]) + p3 * bch(c3a[q]);
          pa[q] = bcu(s);
          f16x2 s2 = p0 * bch(c0b[q]) + p1 * bch(c1b[q])
                   + p2 * bch(c2b[q]) + p3 * bch(c3b[q]);
          pb2[q] = bcu(s2);
        }
        f16x4 a0 = fq(pa[0],  pa[1]);
        f16x4 a1 = fq(pa[2],  pa[3]);
        f16x4 a2 = fq(pb2[0], pb2[1]);
        f16x4 a3 = fq(pb2[2], pb2[3]);
        const char* wbase = (const char*)wtx
                          + (((size_t)(base + i) * 4) * 64 + l) * 32;
        #pragma unroll
        for (int nb = 0; nb < 4; ++nb) {
          const char* wp = wbase + (size_t)nb * (64 * 32);
          uint4v u0 = *(const uint4v*)wp;
          uint4v u1 = *(const uint4v*)(wp + 16);
          acc[nb] = MFMA16(a0, fq(u0[0], u0[1]), acc[nb]);
          acc[nb] = MFMA16(a1, fq(u0[2], u0[3]), acc[nb]);
          acc[nb] = MFMA16(a2, fq(u1[0], u1[1]), acc[nb]);
          acc[nb] = MFMA16(a3, fq(u1[2], u1[3]), acc[nb]);
        }
      }
    }
  }
  __syncthreads();   // xwin dead; accx (alias) exchange

  // ---- P4: group1 -> accx, group0 adds + stores (verified R17..R22) ----
  if (grp == 1) {
    #pragma unroll
    for (int nb = 0; nb < 4; ++nb)
      *(f32x4*)&accx[(nb * 16 + lr) * 68 + (wv & 3) * 16 + lh * 4] = acc[nb];
  }
  __syncthreads();
  if (grp == 0) {
    float* ob = out + (size_t)b * OO * HW;
    #pragma unroll
    for (int nb = 0; nb < 4; ++nb) {
      f32x4 other = *(const f32x4*)&accx[(nb * 16 + lr) * 68 + (wv & 3) * 16 + lh * 4];
      f32x4 v = acc[nb] + other;
      int o = nb * 16 + lr;
      int m = (wv & 3) * 16 + lh * 4;
      int base2 = hw0 + (m >> 5) * WW + (m & 31);
      *(f32x4*)(ob + (size_t)o * HW + base2) = v;
    }
  }
}

extern "C" void kernel_launch(void* const* d_in, const int* in_sizes, int n_in,
                              void* d_out, int out_size, void* d_ws, size_t ws_size,
                              hipStream_t stream) {
  const float* x     = (const float*)d_in[0];
  const float* w_off = (const float*)d_in[1];
  const float* b_off = (const float*)d_in[2];
  const float* w_dcn = (const float*)d_in[3];
  float* out = (float*)d_out;

  char* ws = (char*)d_ws;
  unsigned short* xtp  = (unsigned short*)ws;                      // 9,437,184 B
  unsigned short* wtx  = (unsigned short*)(ws + 9437184);          //    73,728 B
  unsigned short* wofx = (unsigned short*)(ws + 9437184 + 73728);  //    36,864 B
  unsigned short* zp   = (unsigned short*)(ws + 9437184 + 73728 + 36864); // 128 B

  transpose_kernel<<<NPIX / 64, 256, 0, stream>>>(x, xtp);
  prep_kernel<<<(36864 + 18432) / 256, 256, 0, stream>>>(w_dcn, w_off, wtx, wofx, zp);
  fused_kernel<<<NPIX / MT, 512, 0, stream>>>(xtp, wofx, b_off, wtx, zp, out);
}

// Round 24
// 40.023 us; speedup vs baseline: 1.5151x; 1.0501x over previous
//
#include <hip/hip_runtime.h>

#define BB 8
#define CC 64
#define HH 96
#define WW 96
#define OO 64
#define KK 3
#define K2 9
#define HW (HH*WW)      // 9216
#define NOFF 18
#define NPIX (BB*HW)    // 73728
#define MT 64           // pixels per fused block: 2 rows x 32 cols (R20-verified)
#define NTILE (HW/MT)   // 144 tiles per image
#define NXCD 8
#define WR 6
#define WC 36
#define NWIN (WR*WC)    // 216 window pixel-rows, 128 B each (seg-swizzled)
#define OSTR 21         // offs row stride (floats)

typedef _Float16 f16;
typedef __attribute__((ext_vector_type(2))) _Float16 f16x2;
typedef __attribute__((ext_vector_type(4))) _Float16 f16x4;
typedef __attribute__((ext_vector_type(4))) float f32x4;
typedef __attribute__((ext_vector_type(2))) unsigned int uint2v;
typedef __attribute__((ext_vector_type(4))) unsigned int uint4v;

#define MFMA16(a,b,c) __builtin_amdgcn_mfma_f32_16x16x16f16(a,b,c,0,0,0)

typedef const unsigned int __attribute__((address_space(1))) gau32;
typedef unsigned int __attribute__((address_space(3))) lau32;

__device__ __forceinline__ f16x2 bch(unsigned u) { return __builtin_bit_cast(f16x2, u); }
__device__ __forceinline__ unsigned bcu(f16x2 h) { return __builtin_bit_cast(unsigned, h); }
__device__ __forceinline__ f16x4 fq(unsigned a, unsigned b) {
  uint2v u = {a, b};
  return __builtin_bit_cast(f16x4, u);
}
__device__ __forceinline__ f16x4 fq2(uint2v u) { return __builtin_bit_cast(f16x4, u); }
__device__ __forceinline__ int xcd_remap(int bid, int per) {
  return (bid & 7) * per + (bid >> 3);
}

// ---- Kernel T+P: transpose (verified R5) + merged weight prep (R23) --------
// Blocks 0..215 additionally handle one 256-element prep strip (independent
// outputs, no sync needed). wtx/wofx layouts R19/R23-verified.
__global__ __launch_bounds__(256) void transpose_prep_kernel(
    const float* __restrict__ x, unsigned short* __restrict__ xt,
    const float* __restrict__ w_dcn, const float* __restrict__ w_off,
    unsigned short* __restrict__ wtx, unsigned short* __restrict__ wofx,
    unsigned short* __restrict__ zp) {
  int t = threadIdx.x;
  int px = xcd_remap(blockIdx.x, NPIX / 64 / NXCD) * 64 + (t & 63);
  int cg = t >> 6;
  int b = px / HW, hw = px % HW;
  const float* xp = x + (size_t)b * CC * HW + (size_t)(cg * 16) * HW + hw;
  f16 r[16];
  #pragma unroll
  for (int i = 0; i < 16; ++i) r[i] = (f16)xp[i * HW];
  uint4v v0, v1;
  #pragma unroll
  for (int q = 0; q < 4; ++q) {
    f16x2 a = {r[q*2], r[q*2+1]};       v0[q] = bcu(a);
    f16x2 bq = {r[8+q*2], r[8+q*2+1]};  v1[q] = bcu(bq);
  }
  uint4v* dst = (uint4v*)(xt + (size_t)px * CC + cg * 16);
  dst[0] = v0; dst[1] = v1;

  // ---- merged prep strip (blocks 0..215) ----
  if (blockIdx.x < (36864 + 18432) / 256) {
    int idx = blockIdx.x * 256 + t;
    if (idx < 64) zp[idx] = 0;                // 128-B zero page
    if (idx < 36864) {
      int e = idx & 15;
      int l = (idx >> 4) & 63;
      int nb = (idx >> 10) & 3;
      int k = idx >> 12;
      int c = 16 * (l >> 4) + e;
      int o = nb * 16 + (l & 15);
      f16 h = (f16)w_dcn[(o * CC + c) * K2 + k];
      wtx[idx] = __builtin_bit_cast(unsigned short, h);
    } else {
      int i2 = idx - 36864;
      int m = i2 & 15;                        // m = q*4 + e
      int l = (i2 >> 4) & 63;
      int n = (i2 >> 10) & 1;
      int kt = i2 >> 11;
      int q = m >> 2, e = m & 3;
      int c = q * 16 + 4 * (l >> 4) + e;
      int j = n * 16 + (l & 15);
      f16 h = (f16)((j < NOFF) ? w_off[(j * CC + c) * K2 + kt] : 0.f);
      wofx[i2] = __builtin_bit_cast(unsigned short, h);
    }
  }
}

// ---------------- Kernel F: fused offconv(MFMA) + dcn(MFMA) — R23 exact -----
#define XWIN_OFF 0
#define OFFS_OFF 27648
#define ACCX_OFF 0        // aliases xwin (dead after P3)
#define SMEM_SZ  33024

__global__ __launch_bounds__(512, 4) void fused_kernel(
    const unsigned short* __restrict__ xt,    // [B][HW][C] f16
    const unsigned short* __restrict__ wofx,  // [K2][2][64][16] f16
    const float* __restrict__ b_off,          // [18] fp32
    const unsigned short* __restrict__ wtx,   // [K2][4][64][16] f16
    const unsigned short* __restrict__ zp,    // 128-B zero page
    float* __restrict__ out) {
  __shared__ __align__(16) char smem[SMEM_SZ];
  char* xwin = smem + XWIN_OFF;              // 216 x 128 B, seg-swizzled
  float* offs = (float*)(smem + OFFS_OFF);   // [64][21]
  float* accx = (float*)(smem + ACCX_OFF);   // [64 o][68 px] (aliases xwin)

  int t = threadIdx.x;
  int blk = xcd_remap(blockIdx.x, NPIX / MT / NXCD);
  int b = blk / NTILE;
  int ti = blk % NTILE;
  int tr = ti / 3, tc = ti % 3;
  int h0 = tr * 2, w0 = tc * 32;
  int hw0 = h0 * WW + w0;

  const char* xb = (const char*)(xt + (size_t)b * HW * CC);

  // ---- P0: stage window via global_load_lds (R23-verified; rule #21) ----
  #pragma unroll
  for (int r = 0; r < 4; ++r) {
    int d = r * 512 + t;                     // 16-B chunk id, 1728 = 27 waves
    if (d < NWIN * 8) {                      // wave-uniform (27 full waves)
      int row = d >> 3, pos = d & 7;
      int wr_ = row / WC, wc_ = row - wr_ * WC;
      int gy = h0 - 2 + wr_;
      int gx = w0 - 2 + wc_;
      int sg = pos ^ (row & 7);              // content seg for this slot
      const char* src = (((unsigned)gy < HH) && ((unsigned)gx < WW))
          ? xb + (size_t)((gy * WW + gx) << 7) + (sg << 4)
          : (const char*)zp + (sg << 4);
      __builtin_amdgcn_global_load_lds((gau32*)src, (lau32*)(xwin + d * 16),
                                       16, 0, 0);
    }
  }
  __syncthreads();   // compiler drains vmcnt(0) before barrier -> loads landed

  // wave geometry (verified R9/R12)
  int wv = t >> 6;
  int l  = t & 63;
  int lr = l & 15, lh = l >> 4;

  // ---- P1: offset conv via MFMA (R20/R22/R23 math; wofx b128 reads) ----
  {
    int m = wv & 3, n = wv >> 2;             // 4 pixel-tiles x 2 j-tiles
    int p = m * 16 + lr;
    int prow = ((p >> 5) + 1) * WC + (p & 31) + 1;  // window row at ky=kx=0
    f32x4 accO = (f32x4){0.f, 0.f, 0.f, 0.f};
    __builtin_amdgcn_s_setprio(1);
    #pragma unroll
    for (int kt = 0; kt < K2; ++kt) {
      int wrow = prow + (kt / 3) * WC + (kt % 3);
      int rs = wrow & 7;
      const char* bp = (const char*)wofx + (((size_t)(kt * 2 + n)) * 64 + l) * 32;
      uint4v bw0 = *(const uint4v*)bp;        // q=0 (words 0,1), q=1 (2,3)
      uint4v bw1 = *(const uint4v*)(bp + 16); // q=2, q=3
      #pragma unroll
      for (int q = 0; q < 4; ++q) {
        uint2v a2 = *(const uint2v*)&xwin[wrow * 128
                      + ((((q << 1) + (lh >> 1)) ^ rs) << 4) + ((lh & 1) << 3)];
        uint2v b2;
        if (q == 0)      { b2[0] = bw0[0]; b2[1] = bw0[1]; }
        else if (q == 1) { b2[0] = bw0[2]; b2[1] = bw0[3]; }
        else if (q == 2) { b2[0] = bw1[0]; b2[1] = bw1[1]; }
        else             { b2[0] = bw1[2]; b2[1] = bw1[3]; }
        accO = MFMA16(fq2(a2), fq2(b2), accO);
      }
    }
    __builtin_amdgcn_s_setprio(0);
    int j = n * 16 + lr;
    if (j < NOFF) {
      float bj = b_off[j];
      #pragma unroll
      for (int r = 0; r < 4; ++r) {
        int px = m * 16 + lh * 4 + r;        // D row = pixel (R9 map)
        offs[px * OSTR + j] = accO[r] + bj;
      }
    }
  }
  __syncthreads();

  // ---- P2: per-lane params for this group's taps (R15/R17/R20 math) ----
  int grp = wv >> 2;
  int base = grp * 5;                  // g0: taps 0..4, g1: taps 5..8
  int cnt  = 5 - grp;
  int Ra = (wv & 3) * 16 + lr;
  int hpix = h0 + (Ra >> 5), wpix = w0 + (Ra & 31);
  int cB = lh * 32;

  unsigned po01[5], po23[5], pw01[5], pw23[5];
  unsigned emask = 0;
  #pragma unroll
  for (int i = 0; i < 5; ++i) {
    po01[i] = 0; po23[i] = 0; pw01[i] = 0; pw23[i] = 0;
    if (i < cnt) {
      int kt = base + i;
      int ky = kt / 3, kx = kt % 3;
      float py = offs[Ra * OSTR + 2 * kt]     + (float)(hpix - 1 + ky);
      float px = offs[Ra * OSTR + 2 * kt + 1] + (float)(wpix - 1 + kx);
      float y0f = floorf(py), x0f = floorf(px);
      float wy = py - y0f, wx = px - x0f;
      int y0 = (int)y0f, x0 = (int)x0f;
      int y1 = y0 + 1, x1 = x0 + 1;
      bool vy0 = (unsigned)y0 < HH, vy1 = (unsigned)y1 < HH;
      bool vx0 = (unsigned)x0 < WW, vx1 = (unsigned)x1 < WW;
      int cy0 = min(max(y0, 0), HH - 1), cy1 = min(max(y1, 0), HH - 1);
      int cx0 = min(max(x0, 0), WW - 1), cx1 = min(max(x1, 0), WW - 1);
      float g00 = (1.f - wy) * (1.f - wx) * ((vy0 && vx0) ? 1.f : 0.f);
      float g01 = (1.f - wy) * wx         * ((vy0 && vx1) ? 1.f : 0.f);
      float g10 = wy * (1.f - wx)         * ((vy1 && vx0) ? 1.f : 0.f);
      float g11 = wy * wx                 * ((vy1 && vx1) ? 1.f : 0.f);
      int ry0 = cy0 - (h0 - 2), ry1 = cy1 - (h0 - 2);
      int rx0 = cx0 - (w0 - 2), rx1 = cx1 - (w0 - 2);
      bool inw = ((unsigned)ry0 < WR) && ((unsigned)ry1 < WR) &&
                 ((unsigned)rx0 < WC) && ((unsigned)rx1 < WC);
      if (inw) {
        po01[i] = (unsigned)((ry0 * WC + rx0) << 7)
                | ((unsigned)((ry0 * WC + rx1) << 7) << 16);
        po23[i] = (unsigned)((ry1 * WC + rx0) << 7)
                | ((unsigned)((ry1 * WC + rx1) << 7) << 16);
      } else {
        po01[i] = (unsigned)(cy0 * WW + cx0)
                | ((unsigned)(cy0 * WW + cx1) << 16) | 0x80000000u;
        po23[i] = (unsigned)(cy1 * WW + cx0)
                | ((unsigned)(cy1 * WW + cx1) << 16);
        emask |= 1u << i;
      }
      f16x2 wa = {(f16)g00, (f16)g01};
      f16x2 wb = {(f16)g10, (f16)g11};
      pw01[i] = bcu(wa);
      pw23[i] = bcu(wb);
    }
  }

  f32x4 acc[4];
  #pragma unroll
  for (int nb = 0; nb < 4; ++nb) acc[nb] = (f32x4){0.f, 0.f, 0.f, 0.f};

  // ---- P3: dcn taps (R19/R20/R22/R23-verified) ----
  #define WREAD(bo, pos) (*(const uint4v*)&xwin[(bo) + ((pos) << 4)])
  if (__ballot(emask != 0) == 0ull) {
    #pragma unroll
    for (int i = 0; i < 5; ++i) {
      if (i < cnt) {
        unsigned e0 = po01[i], e1 = po23[i];
        int i0 = (int)(e0 & 0xffffu), i1 = (int)(e0 >> 16);
        int i2 = (int)(e1 & 0xffffu), i3 = (int)(e1 >> 16);
        int s0 = lh * 2;
        uint4v c0a = WREAD(i0, s0 ^ ((i0 >> 7) & 7));
        uint4v c0b = WREAD(i0, (s0 + 1) ^ ((i0 >> 7) & 7));
        uint4v c1a = WREAD(i1, s0 ^ ((i1 >> 7) & 7));
        uint4v c1b = WREAD(i1, (s0 + 1) ^ ((i1 >> 7) & 7));
        uint4v c2a = WREAD(i2, s0 ^ ((i2 >> 7) & 7));
        uint4v c2b = WREAD(i2, (s0 + 1) ^ ((i2 >> 7) & 7));
        uint4v c3a = WREAD(i3, s0 ^ ((i3 >> 7) & 7));
        uint4v c3b = WREAD(i3, (s0 + 1) ^ ((i3 >> 7) & 7));
        f16x2 wA = bch(pw01[i]), wB = bch(pw23[i]);
        f16x2 p0 = {wA[0], wA[0]}, p1 = {wA[1], wA[1]};
        f16x2 p2 = {wB[0], wB[0]}, p3 = {wB[1], wB[1]};
        uint4v pa, pb2;
        #pragma unroll
        for (int q = 0; q < 4; ++q) {
          f16x2 s  = p0 * bch(c0a[q]) + p1 * bch(c1a[q])
                   + p2 * bch(c2a[q]) + p3 * bch(c3a[q]);
          pa[q] = bcu(s);
          f16x2 s2 = p0 * bch(c0b[q]) + p1 * bch(c1b[q])
                   + p2 * bch(c2b[q]) + p3 * bch(c3b[q]);
          pb2[q] = bcu(s2);
        }
        f16x4 a0 = fq(pa[0],  pa[1]);
        f16x4 a1 = fq(pa[2],  pa[3]);
        f16x4 a2 = fq(pb2[0], pb2[1]);
        f16x4 a3 = fq(pb2[2], pb2[3]);
        const char* wbase = (const char*)wtx
                          + (((size_t)(base + i) * 4) * 64 + l) * 32;
        __builtin_amdgcn_s_setprio(1);
        #pragma unroll
        for (int nb = 0; nb < 4; ++nb) {
          const char* wp = wbase + (size_t)nb * (64 * 32);
          uint4v u0 = *(const uint4v*)wp;
          uint4v u1 = *(const uint4v*)(wp + 16);
          acc[nb] = MFMA16(a0, fq(u0[0], u0[1]), acc[nb]);
          acc[nb] = MFMA16(a1, fq(u0[2], u0[3]), acc[nb]);
          acc[nb] = MFMA16(a2, fq(u1[0], u1[1]), acc[nb]);
          acc[nb] = MFMA16(a3, fq(u1[2], u1[3]), acc[nb]);
        }
        __builtin_amdgcn_s_setprio(0);
      }
    }
  } else {
    #pragma unroll
    for (int i = 0; i < 5; ++i) {
      if (i < cnt) {
        unsigned e0 = po01[i], e1 = po23[i];
        uint4v c0a, c0b, c1a, c1b, c2a, c2b, c3a, c3b;
        if ((int)e0 >= 0) {
          int i0 = (int)(e0 & 0xffffu), i1 = (int)(e0 >> 16);
          int i2 = (int)(e1 & 0xffffu), i3 = (int)(e1 >> 16);
          int s0 = lh * 2;
          c0a = WREAD(i0, s0 ^ ((i0 >> 7) & 7));
          c0b = WREAD(i0, (s0 + 1) ^ ((i0 >> 7) & 7));
          c1a = WREAD(i1, s0 ^ ((i1 >> 7) & 7));
          c1b = WREAD(i1, (s0 + 1) ^ ((i1 >> 7) & 7));
          c2a = WREAD(i2, s0 ^ ((i2 >> 7) & 7));
          c2b = WREAD(i2, (s0 + 1) ^ ((i2 >> 7) & 7));
          c3a = WREAD(i3, s0 ^ ((i3 >> 7) & 7));
          c3b = WREAD(i3, (s0 + 1) ^ ((i3 >> 7) & 7));
        } else {
          int i0 = (int)(e0 & 0x7fffu) << 7;
          int i1 = (int)((e0 >> 16) & 0x7fffu) << 7;
          int i2 = (int)(e1 & 0x7fffu) << 7;
          int i3 = (int)((e1 >> 16) & 0x7fffu) << 7;
          c0a = *(const uint4v*)(xb + i0 + cB);
          c0b = *(const uint4v*)(xb + i0 + cB + 16);
          c1a = *(const uint4v*)(xb + i1 + cB);
          c1b = *(const uint4v*)(xb + i1 + cB + 16);
          c2a = *(const uint4v*)(xb + i2 + cB);
          c2b = *(const uint4v*)(xb + i2 + cB + 16);
          c3a = *(const uint4v*)(xb + i3 + cB);
          c3b = *(const uint4v*)(xb + i3 + cB + 16);
        }
        f16x2 wA = bch(pw01[i]), wB = bch(pw23[i]);
        f16x2 p0 = {wA[0], wA[0]}, p1 = {wA[1], wA[1]};
        f16x2 p2 = {wB[0], wB[0]}, p3 = {wB[1], wB[1]};
        uint4v pa, pb2;
        #pragma unroll
        for (int q = 0; q < 4; ++q) {
          f16x2 s  = p0 * bch(c0a[q]) + p1 * bch(c1a[q])
                   + p2 * bch(c2a[q]) + p3 * bch(c3a[q]);
          pa[q] = bcu(s);
          f16x2 s2 = p0 * bch(c0b[q]) + p1 * bch(c1b[q])
                   + p2 * bch(c2b[q]) + p3 * bch(c3b[q]);
          pb2[q] = bcu(s2);
        }
        f16x4 a0 = fq(pa[0],  pa[1]);
        f16x4 a1 = fq(pa[2],  pa[3]);
        f16x4 a2 = fq(pb2[0], pb2[1]);
        f16x4 a3 = fq(pb2[2], pb2[3]);
        const char* wbase = (const char*)wtx
                          + (((size_t)(base + i) * 4) * 64 + l) * 32;
        #pragma unroll
        for (int nb = 0; nb < 4; ++nb) {
          const char* wp = wbase + (size_t)nb * (64 * 32);
          uint4v u0 = *(const uint4v*)wp;
          uint4v u1 = *(const uint4v*)(wp + 16);
          acc[nb] = MFMA16(a0, fq(u0[0], u0[1]), acc[nb]);
          acc[nb] = MFMA16(a1, fq(u0[2], u0[3]), acc[nb]);
          acc[nb] = MFMA16(a2, fq(u1[0], u1[1]), acc[nb]);
          acc[nb] = MFMA16(a3, fq(u1[2], u1[3]), acc[nb]);
        }
      }
    }
  }
  __syncthreads();   // xwin dead; accx (alias) exchange

  // ---- P4: group1 -> accx, group0 adds + stores (verified R17..R23) ----
  if (grp == 1) {
    #pragma unroll
    for (int nb = 0; nb < 4; ++nb)
      *(f32x4*)&accx[(nb * 16 + lr) * 68 + (wv & 3) * 16 + lh * 4] = acc[nb];
  }
  __syncthreads();
  if (grp == 0) {
    float* ob = out + (size_t)b * OO * HW;
    #pragma unroll
    for (int nb = 0; nb < 4; ++nb) {
      f32x4 other = *(const f32x4*)&accx[(nb * 16 + lr) * 68 + (wv & 3) * 16 + lh * 4];
      f32x4 v = acc[nb] + other;
      int o = nb * 16 + lr;
      int m = (wv & 3) * 16 + lh * 4;
      int base2 = hw0 + (m >> 5) * WW + (m & 31);
      *(f32x4*)(ob + (size_t)o * HW + base2) = v;
    }
  }
}

extern "C" void kernel_launch(void* const* d_in, const int* in_sizes, int n_in,
                              void* d_out, int out_size, void* d_ws, size_t ws_size,
                              hipStream_t stream) {
  const float* x     = (const float*)d_in[0];
  const float* w_off = (const float*)d_in[1];
  const float* b_off = (const float*)d_in[2];
  const float* w_dcn = (const float*)d_in[3];
  float* out = (float*)d_out;

  char* ws = (char*)d_ws;
  unsigned short* xtp  = (unsigned short*)ws;                      // 9,437,184 B
  unsigned short* wtx  = (unsigned short*)(ws + 9437184);          //    73,728 B
  unsigned short* wofx = (unsigned short*)(ws + 9437184 + 73728);  //    36,864 B
  unsigned short* zp   = (unsigned short*)(ws + 9437184 + 73728 + 36864); // 128 B

  transpose_prep_kernel<<<NPIX / 64, 256, 0, stream>>>(
      x, xtp, w_dcn, w_off, wtx, wofx, zp);
  fused_kernel<<<NPIX / MT, 512, 0, stream>>>(xtp, wofx, b_off, wtx, zp, out);
}